// Round 1
// baseline (3274.730 us; speedup 1.0000x reference)
//
#include <hip/hip_runtime.h>

// -------- CSR build --------

__global__ void k_deg(const int* __restrict__ dst, int* __restrict__ deg, int E) {
    int e = blockIdx.x * blockDim.x + threadIdx.x;
    if (e < E) atomicAdd(&deg[dst[e]], 1);
}

__global__ void k_scan1(const int* __restrict__ deg, int* __restrict__ partial,
                        int* __restrict__ blockSums, int n) {
    __shared__ int sh[256];
    int i = blockIdx.x * 256 + threadIdx.x;
    int v = (i < n) ? deg[i] : 0;
    sh[threadIdx.x] = v;
    __syncthreads();
    for (int off = 1; off < 256; off <<= 1) {
        int t = (threadIdx.x >= (unsigned)off) ? sh[threadIdx.x - off] : 0;
        __syncthreads();
        sh[threadIdx.x] += t;
        __syncthreads();
    }
    if (i < n) partial[i] = sh[threadIdx.x] - v;  // exclusive within block
    if (threadIdx.x == 255) blockSums[blockIdx.x] = sh[255];
}

__global__ void k_scan2(int* __restrict__ bs, int nb) {
    __shared__ int sh[512];
    int t = threadIdx.x;
    int v = (t < nb) ? bs[t] : 0;
    sh[t] = v;
    __syncthreads();
    for (int off = 1; off < 512; off <<= 1) {
        int u = (t >= off) ? sh[t - off] : 0;
        __syncthreads();
        sh[t] += u;
        __syncthreads();
    }
    if (t < nb) bs[t] = sh[t] - v;  // exclusive
}

__global__ void k_scan3(const int* __restrict__ partial, const int* __restrict__ bs,
                        int* __restrict__ start, int* __restrict__ cursor, int n) {
    int i = blockIdx.x * 256 + threadIdx.x;
    if (i < n) {
        int s = partial[i] + bs[blockIdx.x];
        start[i] = s;
        cursor[i] = s;
    }
}

__global__ void k_scatter(const int* __restrict__ src, const int* __restrict__ dst,
                          int* __restrict__ cursor, int* __restrict__ csr, int E) {
    int e = blockIdx.x * blockDim.x + threadIdx.x;
    if (e < E) {
        int d = dst[e];
        int p = atomicAdd(&cursor[d], 1);
        csr[p] = src[e];
    }
}

// -------- mean aggregation over 128-wide rows: one wave per node --------

__global__ void k_agg128(const float* __restrict__ feat, const int* __restrict__ csr,
                         const int* __restrict__ start, const int* __restrict__ deg,
                         float* __restrict__ agg, int n) {
    int wave = (int)((blockIdx.x * blockDim.x + threadIdx.x) >> 6);
    int lane = threadIdx.x & 63;
    if (wave >= n) return;
    int s = start[wave];
    int d = deg[wave];
    const float2* f2 = (const float2*)feat;
    float2 acc = {0.f, 0.f};
    for (int j = 0; j < d; ++j) {
        int sn = csr[s + j];               // wave-uniform broadcast load
        float2 v = f2[(size_t)sn * 64 + lane];  // 512 B coalesced per wave
        acc.x += v.x;
        acc.y += v.y;
    }
    float inv = 1.0f / (float)max(d, 1);
    float2 r;
    r.x = acc.x * inv;
    r.y = acc.y * inv;
    ((float2*)agg)[(size_t)wave * 64 + lane] = r;
}

// -------- fused dual GEMM: out = act(A@Wl + B@Wr + bias), K=128 --------

template <int FOUT, bool RELU>
__global__ void k_gemm(const float* __restrict__ A, const float* __restrict__ B,
                       const float* __restrict__ Wl, const float* __restrict__ Wr,
                       const float* __restrict__ bias, float* __restrict__ out, int n) {
    const int K = 128;
    const int BN = 64;   // nodes per block
    const int KC = 32;   // K-chunk
    __shared__ float shA[BN][KC];
    __shared__ float shB[BN][KC];
    __shared__ float shWl[KC][FOUT];
    __shared__ float shWr[KC][FOUT];

    const int CT = FOUT / 4;   // threads along out-features (each does 4)
    const int RT = 256 / CT;   // threads along nodes
    const int NR = BN / RT;    // nodes per thread

    int t = threadIdx.x;
    int ct = t % CT;
    int rt = t / CT;
    int node0 = blockIdx.x * BN;

    float acc[NR][4];
#pragma unroll
    for (int r = 0; r < NR; ++r)
#pragma unroll
        for (int j = 0; j < 4; ++j) acc[r][j] = 0.f;

    for (int kc = 0; kc < K; kc += KC) {
#pragma unroll
        for (int i = 0; i < BN * KC / 256; ++i) {
            int idx = t + i * 256;
            int r = idx / KC, c = idx % KC;
            int node = node0 + r;
            float av = 0.f, bv = 0.f;
            if (node < n) {
                av = A[(size_t)node * K + kc + c];
                bv = B[(size_t)node * K + kc + c];
            }
            shA[r][c] = av;
            shB[r][c] = bv;
        }
#pragma unroll
        for (int i = 0; i < KC * FOUT / 256; ++i) {
            int idx = t + i * 256;
            int r = idx / FOUT, c = idx % FOUT;
            shWl[r][c] = Wl[(size_t)(kc + r) * FOUT + c];
            shWr[r][c] = Wr[(size_t)(kc + r) * FOUT + c];
        }
        __syncthreads();

#pragma unroll
        for (int k = 0; k < KC; ++k) {
            float wl[4], wr[4];
#pragma unroll
            for (int j = 0; j < 4; ++j) {
                wl[j] = shWl[k][ct * 4 + j];
                wr[j] = shWr[k][ct * 4 + j];
            }
#pragma unroll
            for (int r = 0; r < NR; ++r) {
                float a = shA[rt * NR + r][k];
                float b = shB[rt * NR + r][k];
#pragma unroll
                for (int j = 0; j < 4; ++j) acc[r][j] += a * wl[j] + b * wr[j];
            }
        }
        __syncthreads();
    }

#pragma unroll
    for (int r = 0; r < NR; ++r) {
        int node = node0 + rt * NR + r;
        if (node < n) {
            float4 v;
            float* vp = &v.x;
#pragma unroll
            for (int j = 0; j < 4; ++j) {
                float u = acc[r][j] + bias[ct * 4 + j];
                if (RELU) u = fmaxf(u, 0.f);
                vp[j] = u;
            }
            *(float4*)(out + (size_t)node * FOUT + ct * 4) = v;
        }
    }
}

// -------- launch --------

extern "C" void kernel_launch(void* const* d_in, const int* in_sizes, int n_in,
                              void* d_out, int out_size, void* d_ws, size_t ws_size,
                              hipStream_t stream) {
    const float* x   = (const float*)d_in[0];
    const int*   ei  = (const int*)d_in[1];
    const float* Wl1 = (const float*)d_in[2];
    const float* Wr1 = (const float*)d_in[3];
    const float* b1  = (const float*)d_in[4];
    const float* Wl2 = (const float*)d_in[5];
    const float* Wr2 = (const float*)d_in[6];
    const float* b2  = (const float*)d_in[7];
    float* out = (float*)d_out;

    int Nn = in_sizes[0] / 128;
    int E  = in_sizes[1] / 2;
    const int* src = ei;
    const int* dst = ei + E;

    char* ws = (char*)d_ws;
    auto alloc = [&](size_t bytes) -> char* {
        char* p = ws;
        ws += (bytes + 255) / 256 * 256;
        return p;
    };
    int* deg       = (int*)alloc((size_t)Nn * 4);
    int* start     = (int*)alloc((size_t)Nn * 4);
    int* cursor    = (int*)alloc((size_t)Nn * 4);
    int* partial   = (int*)alloc((size_t)Nn * 4);
    int* blockSums = (int*)alloc(4096);
    int* csr       = (int*)alloc((size_t)E * 4);
    float* agg1    = (float*)alloc((size_t)Nn * 128 * 4);
    float* h       = (float*)alloc((size_t)Nn * 128 * 4);
    float* agg2    = (float*)alloc((size_t)Nn * 64 * 4);

    hipMemsetAsync(deg, 0, (size_t)Nn * 4, stream);

    int nb = (Nn + 255) / 256;  // 391 for N=100000 (fits single-block scan2)
    k_deg<<<(E + 255) / 256, 256, 0, stream>>>(dst, deg, E);
    k_scan1<<<nb, 256, 0, stream>>>(deg, partial, blockSums, Nn);
    k_scan2<<<1, 512, 0, stream>>>(blockSums, nb);
    k_scan3<<<nb, 256, 0, stream>>>(partial, blockSums, start, cursor, Nn);
    k_scatter<<<(E + 255) / 256, 256, 0, stream>>>(src, dst, cursor, csr, E);

    // layer 1
    k_agg128<<<(Nn + 3) / 4, 256, 0, stream>>>(x, csr, start, deg, agg1, Nn);
    k_gemm<128, true><<<(Nn + 63) / 64, 256, 0, stream>>>(agg1, x, Wl1, Wr1, b1, h, Nn);
    // layer 2
    k_agg128<<<(Nn + 3) / 4, 256, 0, stream>>>(h, csr, start, deg, agg2, Nn);
    k_gemm<64, false><<<(Nn + 63) / 64, 256, 0, stream>>>(agg2, h, Wl2, Wr2, b2, out, Nn);
}